// Round 6
// baseline (296.657 us; speedup 1.0000x reference)
//
#include <hip/hip_runtime.h>

// PointPillarScatter on MI355X (gfx950)
#define GNX 512
#define GNY 512
#define GC  64

typedef float vfloat4 __attribute__((ext_vector_type(4)));
typedef int   vint4   __attribute__((ext_vector_type(4)));

// Step 0: fill cell->pillar map with -1.
__global__ void pp_fill_map(int* __restrict__ map, int n) {
    int i = blockIdx.x * blockDim.x + threadIdx.x;
    if (i < n) map[i] = -1;
}

// Step 1: scatter pillar index p into dense (b, y, x) -> p map. coords int32.
__global__ void pp_scatter_idx(const int* __restrict__ coords,
                               int* __restrict__ map, int P) {
    int p = blockIdx.x * blockDim.x + threadIdx.x;
    if (p >= P) return;
    int b = coords[4 * p + 0];
    int z = coords[4 * p + 1];
    int y = coords[4 * p + 2];
    int x = coords[4 * p + 3];
    map[b * (GNY * GNX) + z + y * GNX + x] = p;
}

// Step 2: gather. Thread = (2 x-quads 64 apart, 8-channel group).
// A wave's two stores per plane are consecutive 1 KiB bursts -> 2 KiB
// contiguous runs per plane (vs 1 KiB in R5); half the threads, 2x ILP.
__global__ void __launch_bounds__(256) pp_gather_out(
        const float* __restrict__ feat, const int* __restrict__ map,
        float* __restrict__ out, int npair) {
    int t = blockIdx.x * blockDim.x + threadIdx.x;    // pair id
    if (t >= npair) return;
    int cg = blockIdx.y;                              // channel group 0..7

    int lane = t & 63;
    int base = (t >> 6) << 7;          // pair s covers quad q = base + 64*s + lane
                                       // base%128==0 -> both quads in same y-row

    vint4 m[2];
    int rowoff[2];
#pragma unroll
    for (int s = 0; s < 2; ++s) {
        int q  = base + (s << 6) + lane;
        int x4 = q & (GNX / 4 - 1);
        int y  = (q >> 7) & (GNY - 1);
        int b  = q >> 16;
        rowoff[s] = (b << 24) + (y << 9) + (x4 << 2);  // b*(64<<18)? no: encode below
        // cell index: b*NY*NX + y*NX + x
        m[s] = *(const vint4*)(map + ((b << 18) + (y << 9) + (x4 << 2)));
        // out base offset for this quad (before channel-plane term):
        rowoff[s] = (b << 24) + (y << 9) + (x4 << 2);  // b*64 planes << 18 = b<<24
    }

    vfloat4 fr[2][4][2];               // [pair s][cell j][k]: channels cg*8+4k..+3
#pragma unroll
    for (int s = 0; s < 2; ++s)
#pragma unroll
        for (int j = 0; j < 4; ++j) {
            fr[s][j][0] = (vfloat4)0.f;
            fr[s][j][1] = (vfloat4)0.f;
        }

#pragma unroll
    for (int s = 0; s < 2; ++s)
#pragma unroll
        for (int j = 0; j < 4; ++j) {
            int pj = m[s][j];
            if (pj >= 0) {
                const vfloat4* fp = (const vfloat4*)(feat + (pj << 6) + (cg << 3));
                fr[s][j][0] = fp[0];
                fr[s][j][1] = fp[1];
            }
        }

    // stores: plane w = cg*8 + 4k + tt; plane stride 1<<18 floats.
    // out offset = rowoff[s] + ((cg*8 + 4k + tt) << 18)
#pragma unroll
    for (int k = 0; k < 2; ++k) {
#pragma unroll
        for (int tt = 0; tt < 4; ++tt) {
            int plane = ((cg << 3) + (k << 2) + tt) << 18;
#pragma unroll
            for (int s = 0; s < 2; ++s) {
                vfloat4 v = { fr[s][0][k][tt], fr[s][1][k][tt],
                              fr[s][2][k][tt], fr[s][3][k][tt] };
                __builtin_nontemporal_store(v, (vfloat4*)(out + plane + rowoff[s]));
            }
        }
    }
}

extern "C" void kernel_launch(void* const* d_in, const int* in_sizes, int n_in,
                              void* d_out, int out_size, void* d_ws, size_t ws_size,
                              hipStream_t stream) {
    const float* feat   = (const float*)d_in[0];
    const int*   coords = (const int*)d_in[1];   // int32 (harness converts int64)
    int P = in_sizes[1] / 4;                     // 120000
    int B = out_size / (GC * GNY * GNX);         // 4
    int* map = (int*)d_ws;
    int mapN = B * GNY * GNX;                    // 1,048,576 ints (4 MiB)

    pp_fill_map<<<(mapN + 255) / 256, 256, 0, stream>>>(map, mapN);
    pp_scatter_idx<<<(P + 255) / 256, 256, 0, stream>>>(coords, map, P);

    int npair = B * GNY * (GNX / 4) / 2;         // 131,072 quad-pairs
    dim3 grid((npair + 255) / 256, GC / 8, 1);   // y-dim = 8 channel groups
    pp_gather_out<<<grid, 256, 0, stream>>>(feat, map, (float*)d_out, npair);
}